// Round 1
// baseline (25431.740 us; speedup 1.0000x reference)
//
#include <hip/hip_runtime.h>

#define BB 64
#define TT 128
#define SS 256
#define HH 2048
#define G4H 8192
#define KSUM 6144

typedef __attribute__((ext_vector_type(4))) float f32x4;
typedef __attribute__((ext_vector_type(8))) _Float16 h16x8;
typedef __attribute__((ext_vector_type(4))) _Float16 h16x4;
typedef __attribute__((ext_vector_type(2))) _Float16 h16x2;

__device__ __forceinline__ f32x4 mfma_f16(f32x4 a, f32x4 b, f32x4 c) {
  asm("v_mfma_f32_16x16x32_f16 %0, %1, %2, %0" : "+v"(c) : "v"(a), "v"(b));
  return c;
}

__device__ __forceinline__ float fast_exp2(float x) { return __builtin_amdgcn_exp2f(x); }
__device__ __forceinline__ float fast_rcp(float x) { return __builtin_amdgcn_rcpf(x); }
__device__ __forceinline__ float fast_tanh(float x) {
  // tanh(x) = 1 - 2/(e^{2x}+1); e^{2x} = 2^{x*2*log2(e)}
  float e = fast_exp2(x * 2.8853900817779268f);
  return 1.0f - 2.0f * fast_rcp(e + 1.0f);
}
__device__ __forceinline__ float fast_sig(float x) {
  return fast_rcp(1.0f + fast_exp2(x * -1.4426950408889634f));
}

// ---------------- conversions ----------------

__global__ void cvt_f32_to_f16(const float* __restrict__ src, _Float16* __restrict__ dst, int n4) {
  int i = blockIdx.x * blockDim.x + threadIdx.x;
  int stride = gridDim.x * blockDim.x;
  for (; i < n4; i += stride) {
    f32x4 v = reinterpret_cast<const f32x4*>(src)[i];
    h16x4 h;
    h[0] = (_Float16)v[0]; h[1] = (_Float16)v[1];
    h[2] = (_Float16)v[2]; h[3] = (_Float16)v[3];
    reinterpret_cast<h16x4*>(dst)[i] = h;
  }
}

// Wg[n'][j], n' = 4*h + g, row = [U_h(g,h) | C_ctx(g,h) | W_y(g,h)], j in [0,6144)
__global__ void build_wg(const float* __restrict__ U, const float* __restrict__ Cc,
                         const float* __restrict__ Wy, const float* __restrict__ bias,
                         _Float16* __restrict__ Wg, float* __restrict__ bperm) {
  int row = blockIdx.x;           // 0..8191
  int g = row & 3, h = row >> 2;
  size_t srow = (size_t)(g * HH + h) * HH;
  const float* srcs[3] = {U + srow, Cc + srow, Wy + srow};
  _Float16* dst = Wg + (size_t)row * KSUM;
#pragma unroll
  for (int chunk = 0; chunk < 6; ++chunk) {
    int j = chunk * 1024 + threadIdx.x * 4;
    const float* s = srcs[chunk >> 1] + (j & (HH - 1));
    f32x4 v = *reinterpret_cast<const f32x4*>(s);
    h16x4 o;
    o[0] = (_Float16)v[0]; o[1] = (_Float16)v[1];
    o[2] = (_Float16)v[2]; o[3] = (_Float16)v[3];
    *reinterpret_cast<h16x4*>(dst + j) = o;
  }
  if (threadIdx.x == 0) bperm[row] = bias[g * HH + h];
}

__global__ void init_state(float* __restrict__ cst, _Float16* __restrict__ hA) {
  int i = blockIdx.x * blockDim.x + threadIdx.x;
  if (i < BB * HH) {
    cst[i] = 0.0f;
    hA[i] = (_Float16)0.0f;
  }
}

// ---------------- per-step kernels ----------------

// q[b,k] = sum_j h[b,j]*W_attr[k,j] + b_attr[k]   (M=64, N=2048, K=2048)
__global__ void qgemm(const _Float16* __restrict__ hIn, const _Float16* __restrict__ Wah,
                      const float* __restrict__ battr, _Float16* __restrict__ qh) {
  int w = threadIdx.x >> 6, l = threadIdx.x & 63;
  int col = blockIdx.x * 64 + w * 16 + (l & 15);
  int klane = (l >> 4) * 8;
  int ar = l & 15;
  f32x4 acc[4] = {{0,0,0,0},{0,0,0,0},{0,0,0,0},{0,0,0,0}};
  const _Float16* bp = Wah + (size_t)col * HH + klane;
  const _Float16* ap = hIn + (size_t)ar * HH + klane;
  for (int kk = 0; kk < HH / 32; ++kk) {
    f32x4 bf = *reinterpret_cast<const f32x4*>(bp + kk * 32);
#pragma unroll
    for (int mt = 0; mt < 4; ++mt) {
      f32x4 af = *reinterpret_cast<const f32x4*>(ap + (size_t)mt * 16 * HH + kk * 32);
      acc[mt] = mfma_f16(af, bf, acc[mt]);
    }
  }
  float bias = battr[col];
  int rbase = (l >> 4) * 4;
#pragma unroll
  for (int mt = 0; mt < 4; ++mt)
#pragma unroll
    for (int r = 0; r < 4; ++r) {
      int row = mt * 16 + rbase + r;
      qh[(size_t)row * HH + col] = (_Float16)(acc[mt][r] + bias);
    }
}

// e[b,s] = mask*sum_k V[k]*tanh(kh[b,s,k] + q[b,k]) + (1-mask)*(-1e5)
__global__ void energies(const _Float16* __restrict__ kh, const _Float16* __restrict__ qh,
                         const float* __restrict__ V, const float* __restrict__ mask,
                         float* __restrict__ e) {
  __shared__ float qv[HH];
  __shared__ float vv[HH];
  int b = blockIdx.x >> 5, sg = blockIdx.x & 31;
  int tid = threadIdx.x;
  {
    int i = tid * 8;
    h16x8 q8 = *reinterpret_cast<const h16x8*>(qh + (size_t)b * HH + i);
#pragma unroll
    for (int j = 0; j < 8; ++j) qv[i + j] = (float)q8[j];
    f32x4 v0 = *reinterpret_cast<const f32x4*>(V + i);
    f32x4 v1 = *reinterpret_cast<const f32x4*>(V + i + 4);
#pragma unroll
    for (int j = 0; j < 4; ++j) { vv[i + j] = v0[j]; vv[i + 4 + j] = v1[j]; }
  }
  __syncthreads();
  int sl = tid >> 5, ln = tid & 31;
  int s = sg * 8 + sl;
  const _Float16* row = kh + (size_t)(b * SS + s) * HH;
  float acc = 0.0f;
  for (int ch = 0; ch < 8; ++ch) {
    int k = ch * 256 + ln * 8;
    h16x8 ek = *reinterpret_cast<const h16x8*>(row + k);
#pragma unroll
    for (int j = 0; j < 8; ++j) {
      float x = (float)ek[j] + qv[k + j];
      acc += vv[k + j] * fast_tanh(x);
    }
  }
#pragma unroll
  for (int off = 16; off > 0; off >>= 1) acc += __shfl_xor(acc, off);
  if (ln == 0) {
    float m = mask[b * SS + s];
    e[b * SS + s] = m * acc + (1.0f - m) * (-100000.0f);
  }
}

// softmax over s (per b), ctx[b,c] = sum_s p[s]*ev[b,s,c]; writes ctx (f32 out + f16 scratch)
__global__ void ctx_softmax(const float* __restrict__ e, const _Float16* __restrict__ evh,
                            _Float16* __restrict__ ctxh, float* __restrict__ outCtx, int t) {
  __shared__ float pb[SS];
  __shared__ float red[SS];
  int b = blockIdx.x >> 2, cg = blockIdx.x & 3;
  int tid = threadIdx.x;
  float ev = e[b * SS + tid];
  red[tid] = ev;
  __syncthreads();
  for (int s2 = 128; s2 > 0; s2 >>= 1) {
    if (tid < s2) red[tid] = fmaxf(red[tid], red[tid + s2]);
    __syncthreads();
  }
  float mx = red[0];
  __syncthreads();
  float p = fast_exp2((ev - mx) * 1.4426950408889634f);
  pb[tid] = p;
  red[tid] = p;
  __syncthreads();
  for (int s2 = 128; s2 > 0; s2 >>= 1) {
    if (tid < s2) red[tid] += red[tid + s2];
    __syncthreads();
  }
  float rs = fast_rcp(red[0]);
  int c = cg * 512 + tid * 2;
  const _Float16* base = evh + (size_t)b * SS * HH + c;
  float a0 = 0.0f, a1 = 0.0f;
#pragma unroll 4
  for (int s = 0; s < SS; ++s) {
    h16x2 v = *reinterpret_cast<const h16x2*>(base + (size_t)s * HH);
    float ps = pb[s];
    a0 += ps * (float)v[0];
    a1 += ps * (float)v[1];
  }
  a0 *= rs; a1 *= rs;
  float* oc = outCtx + (size_t)(b * TT + t) * HH + c;
  oc[0] = a0; oc[1] = a1;
  h16x2 hv; hv[0] = (_Float16)a0; hv[1] = (_Float16)a1;
  *reinterpret_cast<h16x2*>(ctxh + (size_t)b * HH + c) = hv;
}

// gates[b,n'] = bperm[n'] + sum_j h*U + ctx*C + y_t*Wy  (K=6144), then fused LSTM cell.
// n' = 4*h_idx + gate, so each 64-col block tile holds all 4 gates for 16 h-indices.
__global__ void gates_cell(const _Float16* __restrict__ hIn, const _Float16* __restrict__ ctxh,
                           const _Float16* __restrict__ yh, const _Float16* __restrict__ Wg,
                           const float* __restrict__ bperm, float* __restrict__ cst,
                           float* __restrict__ outH, _Float16* __restrict__ hOut, int t) {
  __shared__ float glds[64 * 65];
  int w = threadIdx.x >> 6, l = threadIdx.x & 63;
  int col = blockIdx.x * 64 + w * 16 + (l & 15);
  int klane = (l >> 4) * 8;
  int ar = l & 15;
  f32x4 acc[4] = {{0,0,0,0},{0,0,0,0},{0,0,0,0},{0,0,0,0}};
  const _Float16* bp = Wg + (size_t)col * KSUM + klane;
  // segment 0: h @ U
  {
    const _Float16* ap = hIn + (size_t)ar * HH + klane;
    for (int kk = 0; kk < 64; ++kk) {
      f32x4 bf = *reinterpret_cast<const f32x4*>(bp + kk * 32);
#pragma unroll
      for (int mt = 0; mt < 4; ++mt) {
        f32x4 af = *reinterpret_cast<const f32x4*>(ap + (size_t)mt * 16 * HH + kk * 32);
        acc[mt] = mfma_f16(af, bf, acc[mt]);
      }
    }
  }
  // segment 1: ctx @ C
  {
    const _Float16* ap = ctxh + (size_t)ar * HH + klane;
    const _Float16* bp1 = bp + HH;
    for (int kk = 0; kk < 64; ++kk) {
      f32x4 bf = *reinterpret_cast<const f32x4*>(bp1 + kk * 32);
#pragma unroll
      for (int mt = 0; mt < 4; ++mt) {
        f32x4 af = *reinterpret_cast<const f32x4*>(ap + (size_t)mt * 16 * HH + kk * 32);
        acc[mt] = mfma_f16(af, bf, acc[mt]);
      }
    }
  }
  // segment 2: y_t @ Wy  (yh is [B][T][I])
  {
    const _Float16* ap = yh + ((size_t)ar * TT + t) * HH + klane;
    const _Float16* bp2 = bp + 2 * HH;
    for (int kk = 0; kk < 64; ++kk) {
      f32x4 bf = *reinterpret_cast<const f32x4*>(bp2 + kk * 32);
#pragma unroll
      for (int mt = 0; mt < 4; ++mt) {
        f32x4 af = *reinterpret_cast<const f32x4*>(ap + (size_t)mt * 16 * TT * HH + kk * 32);
        acc[mt] = mfma_f16(af, bf, acc[mt]);
      }
    }
  }
  float bias = bperm[col];
  int rbase = (l >> 4) * 4;
#pragma unroll
  for (int mt = 0; mt < 4; ++mt)
#pragma unroll
    for (int r = 0; r < 4; ++r)
      glds[(mt * 16 + rbase + r) * 65 + (w * 16 + (l & 15))] = acc[mt][r] + bias;
  __syncthreads();
  int h0 = blockIdx.x * 16;
#pragma unroll
  for (int it = 0; it < 4; ++it) {
    int p = it * 256 + threadIdx.x;
    int b = p >> 4, hl = p & 15;
    float gi = glds[b * 65 + hl * 4 + 0];
    float gf = glds[b * 65 + hl * 4 + 1];
    float go = glds[b * 65 + hl * 4 + 2];
    float gc = glds[b * 65 + hl * 4 + 3];
    float ig = fast_sig(gi), fg = fast_sig(gf), og = fast_sig(go);
    int ci = b * HH + h0 + hl;
    float cN = ig * fast_tanh(gc) + fg * cst[ci];
    float hN = og * fast_tanh(cN);
    cst[ci] = cN;
    outH[(size_t)(b * TT + t) * HH + h0 + hl] = hN;
    hOut[ci] = (_Float16)hN;
  }
}

// ---------------- launcher ----------------

extern "C" void kernel_launch(void* const* d_in, const int* in_sizes, int n_in,
                              void* d_out, int out_size, void* d_ws, size_t ws_size,
                              hipStream_t stream) {
  const float* enc_keys   = (const float*)d_in[0];
  const float* enc_values = (const float*)d_in[1];
  const float* enc_mask   = (const float*)d_in[2];
  const float* y          = (const float*)d_in[3];
  const float* W_attr     = (const float*)d_in[4];
  const float* V_attr     = (const float*)d_in[5];
  const float* b_attr     = (const float*)d_in[6];
  const float* W_y        = (const float*)d_in[7];
  const float* U_h        = (const float*)d_in[8];
  const float* C_ctx      = (const float*)d_in[9];
  const float* bias       = (const float*)d_in[10];

  char* ws = (char*)d_ws;
  size_t off = 0;
  auto alloc = [&](size_t bytes) {
    void* p = ws + off;
    off += (bytes + 255) & ~(size_t)255;
    return p;
  };
  _Float16* kh   = (_Float16*)alloc((size_t)BB * SS * HH * 2);
  _Float16* evh  = (_Float16*)alloc((size_t)BB * SS * HH * 2);
  _Float16* Wah  = (_Float16*)alloc((size_t)HH * HH * 2);
  _Float16* Wg   = (_Float16*)alloc((size_t)G4H * KSUM * 2);
  _Float16* yh   = (_Float16*)alloc((size_t)BB * TT * HH * 2);
  _Float16* hA   = (_Float16*)alloc((size_t)BB * HH * 2);
  _Float16* hB   = (_Float16*)alloc((size_t)BB * HH * 2);
  _Float16* ctxh = (_Float16*)alloc((size_t)BB * HH * 2);
  _Float16* qh   = (_Float16*)alloc((size_t)BB * HH * 2);
  float* e       = (float*)alloc((size_t)BB * SS * 4);
  float* cst     = (float*)alloc((size_t)BB * HH * 4);
  float* bperm   = (float*)alloc((size_t)G4H * 4);
  (void)ws_size; (void)in_sizes; (void)n_in; (void)out_size;

  float* outH = (float*)d_out;
  float* outCtx = outH + (size_t)BB * TT * HH;

  cvt_f32_to_f16<<<2048, 256, 0, stream>>>(enc_keys, kh, BB * SS * HH / 4);
  cvt_f32_to_f16<<<2048, 256, 0, stream>>>(enc_values, evh, BB * SS * HH / 4);
  cvt_f32_to_f16<<<1024, 256, 0, stream>>>(W_attr, Wah, HH * HH / 4);
  cvt_f32_to_f16<<<2048, 256, 0, stream>>>(y, yh, BB * TT * HH / 4);
  build_wg<<<G4H, 256, 0, stream>>>(U_h, C_ctx, W_y, bias, Wg, bperm);
  init_state<<<(BB * HH + 255) / 256, 256, 0, stream>>>(cst, hA);

  for (int t = 0; t < TT; ++t) {
    const _Float16* hIn = (t & 1) ? hB : hA;
    _Float16* hOut      = (t & 1) ? hA : hB;
    qgemm<<<HH / 64, 256, 0, stream>>>(hIn, Wah, b_attr, qh);
    energies<<<BB * SS / 8, 256, 0, stream>>>(kh, qh, V_attr, enc_mask, e);
    ctx_softmax<<<BB * 4, 256, 0, stream>>>(e, evh, ctxh, outCtx, t);
    gates_cell<<<G4H / 64, 256, 0, stream>>>(hIn, ctxh, yh, Wg, bperm, cst, outH, hOut, t);
  }
}

// Round 3
// 15174.899 us; speedup vs baseline: 1.6759x; 1.6759x over previous
//
#include <hip/hip_runtime.h>

#define BB 64
#define TT 128
#define SS 256
#define HH 2048
#define G4H 8192
#define KSUM 6144
#define NKK_G 192   // KSUM/32
#define NKK_A 64    // HH/32

typedef __attribute__((ext_vector_type(4))) float f32x4;
typedef __attribute__((ext_vector_type(8))) _Float16 h16x8;
typedef __attribute__((ext_vector_type(4))) _Float16 h16x4;
typedef __attribute__((ext_vector_type(2))) _Float16 h16x2;

__device__ __forceinline__ f32x4 mfma16(h16x8 a, h16x8 b, f32x4 c) {
  return __builtin_amdgcn_mfma_f32_16x16x32_f16(a, b, c, 0, 0, 0);
}

__device__ __forceinline__ float fast_exp2(float x) { return __builtin_amdgcn_exp2f(x); }
__device__ __forceinline__ float fast_rcp(float x) { return __builtin_amdgcn_rcpf(x); }
__device__ __forceinline__ float fast_tanh(float x) {
  float e = fast_exp2(x * 2.8853900817779268f);
  return 1.0f - 2.0f * fast_rcp(e + 1.0f);
}
__device__ __forceinline__ float fast_sig(float x) {
  return fast_rcp(1.0f + fast_exp2(x * -1.4426950408889634f));
}

// ---------------- prep kernels ----------------

__global__ void cvt_f32_to_f16(const float* __restrict__ src, _Float16* __restrict__ dst, int n4) {
  int i = blockIdx.x * blockDim.x + threadIdx.x;
  int stride = gridDim.x * blockDim.x;
  for (; i < n4; i += stride) {
    f32x4 v = reinterpret_cast<const f32x4*>(src)[i];
    h16x4 h;
    h[0] = (_Float16)v[0]; h[1] = (_Float16)v[1];
    h[2] = (_Float16)v[2]; h[3] = (_Float16)v[3];
    reinterpret_cast<h16x4*>(dst)[i] = h;
  }
}

// kh[b,s,k] = f16(enc_keys[b,s,k] + b_attr[k])
__global__ void cvt_keys(const float* __restrict__ src, const float* __restrict__ battr,
                         _Float16* __restrict__ dst, int n8) {
  int i = blockIdx.x * blockDim.x + threadIdx.x;
  int stride = gridDim.x * blockDim.x;
  for (; i < n8; i += stride) {
    size_t base = (size_t)i * 8;
    int k = (int)(base & (HH - 1));
    f32x4 v0 = *reinterpret_cast<const f32x4*>(src + base);
    f32x4 v1 = *reinterpret_cast<const f32x4*>(src + base + 4);
    f32x4 b0 = *reinterpret_cast<const f32x4*>(battr + k);
    f32x4 b1 = *reinterpret_cast<const f32x4*>(battr + k + 4);
    h16x8 o;
#pragma unroll
    for (int j = 0; j < 4; ++j) { o[j] = (_Float16)(v0[j] + b0[j]); o[4 + j] = (_Float16)(v1[j] + b1[j]); }
    *reinterpret_cast<h16x8*>(dst + base) = o;
  }
}

// yT[t][b][i] = f16(y[b][t][i])
__global__ void transpose_y(const float* __restrict__ y, _Float16* __restrict__ yT) {
  int blk = blockIdx.x;             // B*T blocks
  int b = blk / TT, t = blk - b * TT;
  int i = threadIdx.x * 8;
  const float* s = y + ((size_t)b * TT + t) * HH + i;
  f32x4 v0 = *reinterpret_cast<const f32x4*>(s);
  f32x4 v1 = *reinterpret_cast<const f32x4*>(s + 4);
  h16x8 o;
#pragma unroll
  for (int j = 0; j < 4; ++j) { o[j] = (_Float16)v0[j]; o[4 + j] = (_Float16)v1[j]; }
  *reinterpret_cast<h16x8*>(yT + ((size_t)t * BB + b) * HH + i) = o;
}

// Swizzled B layout: frag(ct, kk, lane, i) = W[ct*16 + (lane&15)][kk*32 + (lane>>4)*8 + i]
// stored at ((ct*NKK + kk)*64 + lane)*8 + i  (halves). Wave load at (ct,kk) = 1KB contiguous.

// Wgs: cols are n' = 4*h + g (gate-interleaved), rows = [U_h | C_ctx | W_y] over K=6144.
__global__ void build_wgs(const float* __restrict__ U, const float* __restrict__ Cc,
                          const float* __restrict__ Wy, const float* __restrict__ bias,
                          _Float16* __restrict__ Wgs, float* __restrict__ bperm) {
  int ct = blockIdx.x;              // 0..511
  int kw = threadIdx.x >> 6, l = threadIdx.x & 63;
  int c = ct * 16 + (l & 15);
  int g = c & 3, hidx = c >> 2;
  size_t srow = ((size_t)g * HH + hidx) * HH;
  const float* seg[3] = {U + srow, Cc + srow, Wy + srow};
  int koff_lane = (l >> 4) * 8;
  for (int j = 0; j < 48; ++j) {
    int kk = j * 4 + kw;            // 0..191; seg by kk>>6 == j>>4
    const float* s = seg[j >> 4] + (kk & 63) * 32 + koff_lane;
    f32x4 v0 = *reinterpret_cast<const f32x4*>(s);
    f32x4 v1 = *reinterpret_cast<const f32x4*>(s + 4);
    h16x8 o;
#pragma unroll
    for (int q = 0; q < 4; ++q) { o[q] = (_Float16)v0[q]; o[4 + q] = (_Float16)v1[q]; }
    *reinterpret_cast<h16x8*>(Wgs + (((size_t)ct * NKK_G + kk) * 64 + l) * 8) = o;
  }
  if (threadIdx.x < 16) bperm[c] = bias[g * HH + hidx];
}

// Wahs from W_attr [K=2048 rows][H=2048], cols of the GEMM are W_attr rows.
__global__ void build_wahs(const float* __restrict__ W, _Float16* __restrict__ Wahs) {
  int ct = blockIdx.x;              // 0..127
  int kw = threadIdx.x >> 6, l = threadIdx.x & 63;
  int c = ct * 16 + (l & 15);
  const float* row = W + (size_t)c * HH + (l >> 4) * 8;
  for (int j = 0; j < 16; ++j) {
    int kk = j * 4 + kw;            // 0..63
    const float* s = row + kk * 32;
    f32x4 v0 = *reinterpret_cast<const f32x4*>(s);
    f32x4 v1 = *reinterpret_cast<const f32x4*>(s + 4);
    h16x8 o;
#pragma unroll
    for (int q = 0; q < 4; ++q) { o[q] = (_Float16)v0[q]; o[4 + q] = (_Float16)v1[q]; }
    *reinterpret_cast<h16x8*>(Wahs + (((size_t)ct * NKK_A + kk) * 64 + l) * 8) = o;
  }
}

__global__ void init_state(float* __restrict__ cst, _Float16* __restrict__ hA) {
  int i = blockIdx.x * blockDim.x + threadIdx.x;
  if (i < BB * HH) {
    cst[i] = 0.0f;
    hA[i] = (_Float16)0.0f;
  }
}

// ---------------- per-step kernels ----------------

// q[b,k] = sum_j h[b,j]*W_attr[k,j]  (M=64, N=2048, K=2048), bias folded into kh.
// grid = 128 (one 16-col tile each), 4 waves = 4 M-tiles sharing the B stream.
__global__ void qgemm(const _Float16* __restrict__ hIn, const _Float16* __restrict__ Wahs,
                      _Float16* __restrict__ qh) {
  int w = threadIdx.x >> 6, l = threadIdx.x & 63;
  int ct = blockIdx.x;
  const _Float16* bp = Wahs + (size_t)ct * (NKK_A * 512) + l * 8;
  const _Float16* ap = hIn + (size_t)(w * 16 + (l & 15)) * HH + (l >> 4) * 8;
  f32x4 acc0 = {0.f, 0.f, 0.f, 0.f}, acc1 = {0.f, 0.f, 0.f, 0.f};
#pragma unroll 2
  for (int kk = 0; kk < NKK_A; kk += 2) {
    h16x8 b0 = *reinterpret_cast<const h16x8*>(bp + (size_t)kk * 512);
    h16x8 a0 = *reinterpret_cast<const h16x8*>(ap + kk * 32);
    h16x8 b1 = *reinterpret_cast<const h16x8*>(bp + (size_t)(kk + 1) * 512);
    h16x8 a1 = *reinterpret_cast<const h16x8*>(ap + (kk + 1) * 32);
    acc0 = mfma16(a0, b0, acc0);
    acc1 = mfma16(a1, b1, acc1);
  }
  f32x4 acc = acc0 + acc1;
  int col = ct * 16 + (l & 15);
  int rbase = w * 16 + (l >> 4) * 4;
#pragma unroll
  for (int r = 0; r < 4; ++r)
    qh[(size_t)(rbase + r) * HH + col] = (_Float16)acc[r];
}

// e[b,s] = mask*sum_k V[k]*tanh(kh[b,s,k] + q[b,k]) + (1-mask)*(-1e5)
__global__ void energies(const _Float16* __restrict__ kh, const _Float16* __restrict__ qh,
                         const float* __restrict__ V, const float* __restrict__ mask,
                         float* __restrict__ e) {
  __shared__ float qv[HH];
  __shared__ float vv[HH];
  int b = blockIdx.x >> 5, sg = blockIdx.x & 31;
  int tid = threadIdx.x;
  {
    int i = tid * 8;
    h16x8 q8 = *reinterpret_cast<const h16x8*>(qh + (size_t)b * HH + i);
#pragma unroll
    for (int j = 0; j < 8; ++j) qv[i + j] = (float)q8[j];
    f32x4 v0 = *reinterpret_cast<const f32x4*>(V + i);
    f32x4 v1 = *reinterpret_cast<const f32x4*>(V + i + 4);
#pragma unroll
    for (int j = 0; j < 4; ++j) { vv[i + j] = v0[j]; vv[i + 4 + j] = v1[j]; }
  }
  __syncthreads();
  int sl = tid >> 5, ln = tid & 31;
  int s = sg * 8 + sl;
  const _Float16* row = kh + (size_t)(b * SS + s) * HH;
  float acc = 0.0f;
  for (int ch = 0; ch < 8; ++ch) {
    int k = ch * 256 + ln * 8;
    h16x8 ek = *reinterpret_cast<const h16x8*>(row + k);
#pragma unroll
    for (int j = 0; j < 8; ++j) {
      float x = (float)ek[j] + qv[k + j];
      acc += vv[k + j] * fast_tanh(x);
    }
  }
#pragma unroll
  for (int off = 16; off > 0; off >>= 1) acc += __shfl_xor(acc, off);
  if (ln == 0) {
    float m = mask[b * SS + s];
    e[b * SS + s] = m * acc + (1.0f - m) * (-100000.0f);
  }
}

// softmax over s, ctx[b,c] = sum_s p[s]*ev[b,s,c].
// grid = B*4 (512 cols each); 4 waves each own 64 s-rows; 16B/lane 1KB/wave loads.
__global__ void ctx_softmax(const float* __restrict__ e, const _Float16* __restrict__ evh,
                            _Float16* __restrict__ ctxh, float* __restrict__ outCtx, int t) {
  __shared__ float pb[SS];
  __shared__ float red[SS];
  __shared__ float pf[4 * 512];
  int b = blockIdx.x >> 2, cq = blockIdx.x & 3;
  int tid = threadIdx.x;
  float ev = e[b * SS + tid];
  red[tid] = ev;
  __syncthreads();
  for (int s2 = 128; s2 > 0; s2 >>= 1) {
    if (tid < s2) red[tid] = fmaxf(red[tid], red[tid + s2]);
    __syncthreads();
  }
  float mx = red[0];
  __syncthreads();
  float p = fast_exp2((ev - mx) * 1.4426950408889634f);
  pb[tid] = p;
  red[tid] = p;
  __syncthreads();
  for (int s2 = 128; s2 > 0; s2 >>= 1) {
    if (tid < s2) red[tid] += red[tid + s2];
    __syncthreads();
  }
  float rs = fast_rcp(red[0]);
  int sg = tid >> 6, cs = tid & 63;
  const _Float16* base = evh + ((size_t)b * SS + sg * 64) * HH + cq * 512 + cs * 8;
  float acc[8] = {0.f, 0.f, 0.f, 0.f, 0.f, 0.f, 0.f, 0.f};
#pragma unroll 4
  for (int s = 0; s < 64; ++s) {
    h16x8 v = *reinterpret_cast<const h16x8*>(base + (size_t)s * HH);
    float ps = pb[sg * 64 + s];
#pragma unroll
    for (int j = 0; j < 8; ++j) acc[j] += ps * (float)v[j];
  }
#pragma unroll
  for (int j = 0; j < 8; ++j) pf[sg * 512 + cs * 8 + j] = acc[j];
  __syncthreads();
  {
    int c0 = tid * 2;
#pragma unroll
    for (int u = 0; u < 2; ++u) {
      int c = c0 + u;
      float sum = pf[c] + pf[512 + c] + pf[1024 + c] + pf[1536 + c];
      float val = sum * rs;
      outCtx[((size_t)b * TT + t) * HH + cq * 512 + c] = val;
      ctxh[(size_t)b * HH + cq * 512 + c] = (_Float16)val;
    }
  }
}

// gates[b,n'] + fused LSTM cell. grid = 256 blocks of 32 cols; 4 waves = (Mhalf, coltile).
__global__ void gates_cell(const _Float16* __restrict__ hIn, const _Float16* __restrict__ ctxh,
                           const _Float16* __restrict__ yT, const _Float16* __restrict__ Wgs,
                           const float* __restrict__ bperm, float* __restrict__ cst,
                           float* __restrict__ outH, _Float16* __restrict__ hOut, int t) {
  __shared__ float glds[64 * 33];
  int w = threadIdx.x >> 6, l = threadIdx.x & 63;
  int cb = blockIdx.x;
  int mh = w >> 1, cth = w & 1;
  int ctg = cb * 2 + cth;
  const _Float16* bp = Wgs + (size_t)ctg * (NKK_G * 512) + l * 8;
  size_t arow = ((size_t)(mh * 32 + (l & 15))) * HH + (l >> 4) * 8;
  f32x4 acc0 = {0.f, 0.f, 0.f, 0.f}, acc1 = {0.f, 0.f, 0.f, 0.f};
  // segment 0: h @ U
  {
    const _Float16* a = hIn + arow;
#pragma unroll 2
    for (int kk = 0; kk < 64; ++kk) {
      h16x8 bf = *reinterpret_cast<const h16x8*>(bp + (size_t)kk * 512);
      h16x8 af0 = *reinterpret_cast<const h16x8*>(a + kk * 32);
      h16x8 af1 = *reinterpret_cast<const h16x8*>(a + 16 * HH + kk * 32);
      acc0 = mfma16(af0, bf, acc0);
      acc1 = mfma16(af1, bf, acc1);
    }
  }
  // segment 1: ctx @ C
  {
    const _Float16* a = ctxh + arow;
    const _Float16* bp1 = bp + (size_t)64 * 512;
#pragma unroll 2
    for (int kk = 0; kk < 64; ++kk) {
      h16x8 bf = *reinterpret_cast<const h16x8*>(bp1 + (size_t)kk * 512);
      h16x8 af0 = *reinterpret_cast<const h16x8*>(a + kk * 32);
      h16x8 af1 = *reinterpret_cast<const h16x8*>(a + 16 * HH + kk * 32);
      acc0 = mfma16(af0, bf, acc0);
      acc1 = mfma16(af1, bf, acc1);
    }
  }
  // segment 2: y_t @ Wy (yT is time-major)
  {
    const _Float16* a = yT + (size_t)t * BB * HH + arow;
    const _Float16* bp2 = bp + (size_t)128 * 512;
#pragma unroll 2
    for (int kk = 0; kk < 64; ++kk) {
      h16x8 bf = *reinterpret_cast<const h16x8*>(bp2 + (size_t)kk * 512);
      h16x8 af0 = *reinterpret_cast<const h16x8*>(a + kk * 32);
      h16x8 af1 = *reinterpret_cast<const h16x8*>(a + 16 * HH + kk * 32);
      acc0 = mfma16(af0, bf, acc0);
      acc1 = mfma16(af1, bf, acc1);
    }
  }
  float bias = bperm[cb * 32 + cth * 16 + (l & 15)];
  int lcol = cth * 16 + (l & 15);
  int rb = mh * 32 + (l >> 4) * 4;
#pragma unroll
  for (int r = 0; r < 4; ++r) {
    glds[(rb + r) * 33 + lcol] = acc0[r] + bias;
    glds[(rb + 16 + r) * 33 + lcol] = acc1[r] + bias;
  }
  __syncthreads();
  int h0 = cb * 8;
#pragma unroll
  for (int it = 0; it < 2; ++it) {
    int p = it * 256 + threadIdx.x;
    int b = p >> 3, hl = p & 7;
    float gi = glds[b * 33 + hl * 4 + 0];
    float gf = glds[b * 33 + hl * 4 + 1];
    float go = glds[b * 33 + hl * 4 + 2];
    float gc = glds[b * 33 + hl * 4 + 3];
    float ig = fast_sig(gi), fg = fast_sig(gf), og = fast_sig(go);
    int ci = b * HH + h0 + hl;
    float cN = ig * fast_tanh(gc) + fg * cst[ci];
    float hN = og * fast_tanh(cN);
    cst[ci] = cN;
    outH[((size_t)b * TT + t) * HH + h0 + hl] = hN;
    hOut[ci] = (_Float16)hN;
  }
}

// ---------------- launcher ----------------

extern "C" void kernel_launch(void* const* d_in, const int* in_sizes, int n_in,
                              void* d_out, int out_size, void* d_ws, size_t ws_size,
                              hipStream_t stream) {
  const float* enc_keys   = (const float*)d_in[0];
  const float* enc_values = (const float*)d_in[1];
  const float* enc_mask   = (const float*)d_in[2];
  const float* y          = (const float*)d_in[3];
  const float* W_attr     = (const float*)d_in[4];
  const float* V_attr     = (const float*)d_in[5];
  const float* b_attr     = (const float*)d_in[6];
  const float* W_y        = (const float*)d_in[7];
  const float* U_h        = (const float*)d_in[8];
  const float* C_ctx      = (const float*)d_in[9];
  const float* bias       = (const float*)d_in[10];

  char* ws = (char*)d_ws;
  size_t off = 0;
  auto alloc = [&](size_t bytes) {
    void* p = ws + off;
    off += (bytes + 255) & ~(size_t)255;
    return p;
  };
  _Float16* kh   = (_Float16*)alloc((size_t)BB * SS * HH * 2);
  _Float16* evh  = (_Float16*)alloc((size_t)BB * SS * HH * 2);
  _Float16* Wahs = (_Float16*)alloc((size_t)HH * HH * 2);
  _Float16* Wgs  = (_Float16*)alloc((size_t)G4H * KSUM * 2);
  _Float16* yTh  = (_Float16*)alloc((size_t)BB * TT * HH * 2);
  _Float16* hA   = (_Float16*)alloc((size_t)BB * HH * 2);
  _Float16* hB   = (_Float16*)alloc((size_t)BB * HH * 2);
  _Float16* ctxh = (_Float16*)alloc((size_t)BB * HH * 2);
  _Float16* qh   = (_Float16*)alloc((size_t)BB * HH * 2);
  float* e       = (float*)alloc((size_t)BB * SS * 4);
  float* cst     = (float*)alloc((size_t)BB * HH * 4);
  float* bperm   = (float*)alloc((size_t)G4H * 4);
  (void)ws_size; (void)in_sizes; (void)n_in; (void)out_size;

  float* outH = (float*)d_out;
  float* outCtx = outH + (size_t)BB * TT * HH;

  cvt_keys<<<2048, 256, 0, stream>>>(enc_keys, b_attr, kh, BB * SS * HH / 8);
  cvt_f32_to_f16<<<2048, 256, 0, stream>>>(enc_values, evh, BB * SS * HH / 4);
  build_wahs<<<HH / 16, 256, 0, stream>>>(W_attr, Wahs);
  build_wgs<<<G4H / 16, 256, 0, stream>>>(U_h, C_ctx, W_y, bias, Wgs, bperm);
  transpose_y<<<BB * TT, 256, 0, stream>>>(y, yTh);
  init_state<<<(BB * HH + 255) / 256, 256, 0, stream>>>(cst, hA);

  for (int t = 0; t < TT; ++t) {
    const _Float16* hIn = (t & 1) ? hB : hA;
    _Float16* hOut      = (t & 1) ? hA : hB;
    qgemm<<<HH / 16, 256, 0, stream>>>(hIn, Wahs, qh);
    energies<<<BB * SS / 8, 256, 0, stream>>>(kh, qh, V_attr, enc_mask, e);
    ctx_softmax<<<BB * 4, 256, 0, stream>>>(e, evh, ctxh, outCtx, t);
    gates_cell<<<G4H / 32, 256, 0, stream>>>(hIn, ctxh, yTh, Wgs, bperm, cst, outH, hOut, t);
  }
}